// Round 12
// baseline (706.832 us; speedup 1.0000x reference)
//
#include <hip/hip_runtime.h>
#include <hip/hip_bf16.h>

// ---------------------------------------------------------------------------
// Treensformer block: x += MHSA(LN1(x)); x += BranchMLP(LN2(x))
// B=64, N_NODES=341, E=512, H=8, hd=64, 4*E=2048, N_LEVELS=4
// R1: MFMA flash attention. R5: branch-MLP ancestor dedup.
// R6/R7: 256^2 deep pipeline -> REGRESSED. R8: 128^2 + fused branch +
//     XCD/A-major remap: 785us. R9: BK64 + XOR swizzle: 751 (conflicts->0).
// R10: gemm64 for proj/w2: 722 (occupancy 23->45%). R11: split-K: REGRESS.
// R12: ~neutral. R13: gemm64 qkv(-6 WIN) + branch(+26 REGRESS).
// R14: combine-into-w2 staging fusion: REGRESSED HARD.
// R15: best-of-each assembly: 702. WIN. R16: exp2-softmax + LN vec +
//     fused prep: 691. WIN (small).
// R17: the overlooked residency notch: w2/proj grids (1364 blocks =
//     5.33/CU) don't even fill gemm64's 6-block cap. gemm32 (32x128,
//     acc[2][2], 20KB LDS, bounds(256,8)) -> 2728 blocks = 10.7/CU
//     against an 8-block cap = 32 waves/CU (hw max). B-staging identical
//     to gemm64 (no R11 conflict trap); A-staging 1 slot/thread, same
//     XOR. qkv stays gemm64 (control). R10 precedent: occupancy beats
//     per-iteration MFMA density in this latency-bound regime.
// ---------------------------------------------------------------------------

typedef __attribute__((ext_vector_type(8))) __bf16 bf16x8;
typedef __attribute__((ext_vector_type(4))) __bf16 bf16x4;
typedef __attribute__((ext_vector_type(2))) __bf16 bf16x2;
typedef __attribute__((ext_vector_type(4))) float f32x4;
typedef __attribute__((ext_vector_type(2))) float f32x2;
typedef __attribute__((ext_vector_type(4))) unsigned int u32x4;

#define GF_RELU    1
#define GF_OUTBF16 2

static __device__ __forceinline__ bf16x8 bzero8() {
    u32x4 z = {0u, 0u, 0u, 0u};
    return __builtin_bit_cast(bf16x8, z);
}

// ---------------------------------------------------------------------------
// R16 fused prep kernel: all weight prep in ONE dispatch, 4 elems/thread.
// ---------------------------------------------------------------------------
__global__ __launch_bounds__(256) void prep_kernel(
    const float* __restrict__ w_qkv, const float* __restrict__ w_proj,
    const float* __restrict__ w2, const float* __restrict__ M,
    __hip_bfloat16* __restrict__ wqkvT, __hip_bfloat16* __restrict__ wprojT,
    __hip_bfloat16* __restrict__ w2T, __hip_bfloat16* __restrict__ wcat) {
    const int bid = blockIdx.x;
    if (bid < 2048) {
        // transpose jobs
        const float* in;
        __hip_bfloat16* out;
        int N, log2K, loc;
        if (bid < 768)       { in = w_qkv;  out = wqkvT;  N = 1536; log2K = 9;  loc = bid; }
        else if (bid < 1024) { in = w_proj; out = wprojT; N = 512;  log2K = 9;  loc = bid - 768; }
        else                 { in = w2;     out = w2T;    N = 512;  log2K = 11; loc = bid - 1024; }
        int idx4 = (loc * 256 + threadIdx.x) << 2;
        int n = idx4 >> log2K;
        int k = idx4 & ((1 << log2K) - 1);
        bf16x4 o;
        #pragma unroll
        for (int u = 0; u < 4; u++)
            o[u] = (__bf16)__float2bfloat16(in[(size_t)(k + u) * N + n]);
        *(bf16x4*)(out + idx4) = o;
    } else {
        // pack_wcat: 15 (s,d) pairs x 1024 blocks each
        int loc = bid - 2048;
        int p = loc >> 10;          // 0..14
        int blk = loc & 1023;
        int s, d;
        if (p < 5)       { s = 0; d = p; }
        else if (p < 9)  { s = 1; d = p - 4; }
        else if (p < 12) { s = 2; d = p - 7; }
        else if (p < 14) { s = 3; d = p - 9; }
        else             { s = 4; d = 4; }
        const int base_lut[5] = {0, 5, 9, 12, 14};
        size_t idx4 = ((size_t)blk * 256 + threadIdx.x) << 2;
        const size_t MB = 2048ull * 512;
        f32x4 v = *(const f32x4*)(M + ((size_t)d * 5 + s) * MB + idx4);
        bf16x4 o;
        #pragma unroll
        for (int u = 0; u < 4; u++) o[u] = (__bf16)__float2bfloat16(v[u]);
        *(bf16x4*)(wcat + (size_t)base_lut[s] * MB + (size_t)(d - s) * MB + idx4) = o;
    }
}

// ---------------------------------------------------------------------------
// LayerNorm over E=512, one block (256 threads) per token; float2 loads,
// bf16x2 stores (R16 vectorization).
// ---------------------------------------------------------------------------
__global__ __launch_bounds__(256) void ln_kernel(const float* __restrict__ x,
                                                 const float* __restrict__ g,
                                                 const float* __restrict__ b,
                                                 __hip_bfloat16* __restrict__ out) {
    int tok = blockIdx.x;
    const float* xr = x + (size_t)tok * 512;
    int t = threadIdx.x;
    f32x2 v = *(const f32x2*)(xr + 2 * t);
    float s = v[0] + v[1];
    float s2 = v[0] * v[0] + v[1] * v[1];
    #pragma unroll
    for (int o = 32; o > 0; o >>= 1) {
        s  += __shfl_down(s, o);
        s2 += __shfl_down(s2, o);
    }
    __shared__ float ps[4], ps2[4];
    int w = t >> 6, lane = t & 63;
    if (lane == 0) { ps[w] = s; ps2[w] = s2; }
    __syncthreads();
    if (t == 0) {
        float ts = 0.f, ts2 = 0.f;
        #pragma unroll
        for (int i = 0; i < 4; i++) { ts += ps[i]; ts2 += ps2[i]; }
        ps[0] = ts * (1.f / 512.f);
        ps2[0] = ts2 * (1.f / 512.f);
    }
    __syncthreads();
    float m = ps[0];
    float var = ps2[0] - m * m;
    float r = rsqrtf(var + 1e-5f);
    f32x2 gv = *(const f32x2*)(g + 2 * t);
    f32x2 bv = *(const f32x2*)(b + 2 * t);
    bf16x2 o;
    o[0] = (__bf16)__float2bfloat16((v[0] - m) * r * gv[0] + bv[0]);
    o[1] = (__bf16)__float2bfloat16((v[1] - m) * r * gv[1] + bv[1]);
    *(bf16x2*)(out + (size_t)tok * 512 + 2 * t) = o;
}

// ---------------------------------------------------------------------------
// MFMA flash attention (R16: exp2-domain online softmax).
// ---------------------------------------------------------------------------
#define ATT_STR 72
#define SC2 0.18033688f   // 0.125 * log2(e)
__global__ __launch_bounds__(256) void attn_mfma_kernel(const __hip_bfloat16* __restrict__ qkv,
                                                        __hip_bfloat16* __restrict__ ctx) {
    __shared__ __bf16 kt_lds[64 * ATT_STR];
    __shared__ __bf16 vt_lds[64 * ATT_STR];
    __shared__ __bf16 pbuf[4 * 48 * ATT_STR];

    const int bh = blockIdx.x;
    const int half = blockIdx.y;
    const int b = bh >> 3, h = bh & 7;
    const int tid = threadIdx.x;
    const int w = tid >> 6, lane = tid & 63;
    const int q = lane >> 4, l16 = lane & 15;
    const int rowbase = half * 192 + w * 48;
    __bf16* pw = pbuf + w * 48 * ATT_STR;

    bf16x8 qf[3][2];
    #pragma unroll
    for (int mi = 0; mi < 3; mi++) {
        int row = rowbase + mi * 16 + l16;
        #pragma unroll
        for (int ks = 0; ks < 2; ks++) {
            if (row < 341)
                qf[mi][ks] = *(const bf16x8*)(qkv + (size_t)(b * 341 + row) * 1536 +
                                              h * 64 + ks * 32 + q * 8);
            else
                qf[mi][ks] = bzero8();
        }
    }

    f32x4 O[3][4];
    float mrun[3][4], lrun[3][4];
    #pragma unroll
    for (int mi = 0; mi < 3; mi++) {
        #pragma unroll
        for (int ni = 0; ni < 4; ni++) { f32x4 z = {0.f,0.f,0.f,0.f}; O[mi][ni] = z; }
        #pragma unroll
        for (int rr = 0; rr < 4; rr++) { mrun[mi][rr] = -1e30f; lrun[mi][rr] = 0.f; }
    }

    for (int kt6 = 0; kt6 < 6; kt6++) {
        const int kbase = kt6 * 64;
        __syncthreads();
        {
            int key = tid >> 2, kg = tid & 3;
            int gk = kbase + key;
            bf16x8 a0 = bzero8(), a1 = bzero8();
            if (gk < 341) {
                const __hip_bfloat16* src =
                    qkv + (size_t)(b * 341 + gk) * 1536 + 512 + h * 64 + kg * 16;
                a0 = *(const bf16x8*)src;
                a1 = *(const bf16x8*)(src + 8);
            }
            *(bf16x8*)(kt_lds + key * ATT_STR + kg * 16)     = a0;
            *(bf16x8*)(kt_lds + key * ATT_STR + kg * 16 + 8) = a1;
        }
        {
            int key = tid & 63, dg = tid >> 6;
            int gk = kbase + key;
            bf16x8 a0 = bzero8(), a1 = bzero8();
            if (gk < 341) {
                const __hip_bfloat16* src =
                    qkv + (size_t)(b * 341 + gk) * 1536 + 1024 + h * 64 + dg * 16;
                a0 = *(const bf16x8*)src;
                a1 = *(const bf16x8*)(src + 8);
            }
            #pragma unroll
            for (int j = 0; j < 8; j++) {
                vt_lds[(dg * 16 + j) * ATT_STR + key]     = a0[j];
                vt_lds[(dg * 16 + 8 + j) * ATT_STR + key] = a1[j];
            }
        }
        __syncthreads();

        f32x4 S[3][4];
        #pragma unroll
        for (int mi = 0; mi < 3; mi++)
            #pragma unroll
            for (int ni = 0; ni < 4; ni++) { f32x4 z = {0.f,0.f,0.f,0.f}; S[mi][ni] = z; }
        #pragma unroll
        for (int ks = 0; ks < 2; ks++) {
            bf16x8 bf_[4];
            #pragma unroll
            for (int ni = 0; ni < 4; ni++)
                bf_[ni] = *(const bf16x8*)(kt_lds + (ni * 16 + l16) * ATT_STR + ks * 32 + q * 8);
            #pragma unroll
            for (int mi = 0; mi < 3; mi++)
                #pragma unroll
                for (int ni = 0; ni < 4; ni++)
                    S[mi][ni] = __builtin_amdgcn_mfma_f32_16x16x32_bf16(qf[mi][ks], bf_[ni],
                                                                        S[mi][ni], 0, 0, 0);
        }

        float cmask[4];
        #pragma unroll
        for (int ni = 0; ni < 4; ni++)
            cmask[ni] = (kbase + ni * 16 + l16 < 341) ? 0.f : -1e30f;

        #pragma unroll
        for (int mi = 0; mi < 3; mi++) {
            #pragma unroll
            for (int rr = 0; rr < 4; rr++) {
                float rmax = -1e30f;
                #pragma unroll
                for (int ni = 0; ni < 4; ni++)
                    rmax = fmaxf(rmax, fmaf(S[mi][ni][rr], SC2, cmask[ni]));
                rmax = fmaxf(rmax, __shfl_xor(rmax, 1));
                rmax = fmaxf(rmax, __shfl_xor(rmax, 2));
                rmax = fmaxf(rmax, __shfl_xor(rmax, 4));
                rmax = fmaxf(rmax, __shfl_xor(rmax, 8));
                float mnew = fmaxf(mrun[mi][rr], rmax);
                float alpha = exp2f(mrun[mi][rr] - mnew);
                mrun[mi][rr] = mnew;
                float psum = 0.f;
                #pragma unroll
                for (int ni = 0; ni < 4; ni++) {
                    float p = exp2f(fmaf(S[mi][ni][rr], SC2, cmask[ni]) - mnew);
                    S[mi][ni][rr] = p;
                    psum += p;
                    O[mi][ni][rr] *= alpha;
                }
                psum += __shfl_xor(psum, 1);
                psum += __shfl_xor(psum, 2);
                psum += __shfl_xor(psum, 4);
                psum += __shfl_xor(psum, 8);
                lrun[mi][rr] = lrun[mi][rr] * alpha + psum;
            }
            #pragma unroll
            for (int ni = 0; ni < 4; ni++)
                #pragma unroll
                for (int rr = 0; rr < 4; rr++)
                    pw[(mi * 16 + q * 4 + rr) * ATT_STR + ni * 16 + l16] =
                        (__bf16)S[mi][ni][rr];
        }
        __syncthreads();

        #pragma unroll
        for (int ks = 0; ks < 2; ks++) {
            bf16x8 pf[3], vf[4];
            #pragma unroll
            for (int mi = 0; mi < 3; mi++)
                pf[mi] = *(const bf16x8*)(pw + (mi * 16 + l16) * ATT_STR + ks * 32 + q * 8);
            #pragma unroll
            for (int ni = 0; ni < 4; ni++)
                vf[ni] = *(const bf16x8*)(vt_lds + (ni * 16 + l16) * ATT_STR + ks * 32 + q * 8);
            #pragma unroll
            for (int mi = 0; mi < 3; mi++)
                #pragma unroll
                for (int ni = 0; ni < 4; ni++)
                    O[mi][ni] = __builtin_amdgcn_mfma_f32_16x16x32_bf16(pf[mi], vf[ni],
                                                                        O[mi][ni], 0, 0, 0);
        }
    }

    #pragma unroll
    for (int mi = 0; mi < 3; mi++) {
        #pragma unroll
        for (int rr = 0; rr < 4; rr++) {
            int row = rowbase + mi * 16 + q * 4 + rr;
            if (row >= 341) continue;
            float inv = 1.f / lrun[mi][rr];
            __hip_bfloat16* op = ctx + (size_t)(b * 341 + row) * 512 + h * 64;
            #pragma unroll
            for (int ni = 0; ni < 4; ni++)
                op[ni * 16 + l16] = __float2bfloat16(O[mi][ni][rr] * inv);
        }
    }
}

// bijective XCD-aware remap (m204): each XCD gets a contiguous chunk of the
// logical (A-major) tile order -> neighboring tiles sharing an A row-panel
// land on the same XCD's L2.
static __device__ __forceinline__ int xcd_remap(int bid, int nwg) {
    const int xcd = bid & 7, o = bid >> 3;
    const int qq = nwg >> 3, rr = nwg & 7;
    return (xcd < rr ? xcd * (qq + 1) : rr * (qq + 1) + (xcd - rr) * qq) + o;
}

// ---------------------------------------------------------------------------
// gemm128 body (128x128xBK64, register staging, both-sides XOR swizzle).
// Used by the fused branch GEMM only (deep grid; R13 proved 64x128 hurts it).
// ---------------------------------------------------------------------------
template <bool GATHER>
static __device__ __forceinline__ void gemm128_body(
    __hip_bfloat16* As, __hip_bfloat16* Bs,
    const __hip_bfloat16* __restrict__ A, const __hip_bfloat16* __restrict__ Bt,
    const float* __restrict__ bias, const float* __restrict__ resid,
    float* __restrict__ Cf, __hip_bfloat16* __restrict__ Cb,
    int Mrows, int N, int K, int flags, int depth, int bm0, int bn0) {
    const int tid = threadIdx.x;
    const int r = tid >> 1;            // staging row 0..127
    const int khalf = tid & 1;         // 0/1 -> 32-element (64B) half of row
    const int gr = bm0 + r;
    const int gn = bn0 + r;
    const int lane = tid & 63;
    const int w = tid >> 6;
    const int wm = (w >> 1) << 6;
    const int wn = (w & 1) << 6;
    const int q = lane >> 4;
    const int l16 = lane & 15;

    int wsl[4];
    #pragma unroll
    for (int j = 0; j < 4; j++)
        wsl[j] = ((((khalf << 2) | j) ^ (r & 7)) << 3);
    const int rs0 = ((q ^ (l16 & 7)) << 3);
    const int rs1 = (((4 + q) ^ (l16 & 7)) << 3);

    size_t abase;
    if (GATHER) {
        const int dsh = depth << 1;
        const int bmask = (1 << dsh) - 1;
        int b = gr >> dsh;
        int i = gr & bmask;
        int node = (0x55555555 & bmask) + i;   // offs[depth] + i
        abase = ((size_t)(b * 341 + node)) << 9;
    } else {
        abase = (size_t)gr * K;
    }

    f32x4 acc[4][4];
    #pragma unroll
    for (int i = 0; i < 4; i++)
        #pragma unroll
        for (int j = 0; j < 4; j++) {
            f32x4 z = {0.f, 0.f, 0.f, 0.f};
            acc[i][j] = z;
        }

    for (int k0 = 0; k0 < K; k0 += 64) {
        bf16x8 va[4], vb[4];
        if (gr < Mrows) {
            const bf16x8* p = (const bf16x8*)(A + abase + k0 + (khalf << 5));
            #pragma unroll
            for (int j = 0; j < 4; j++) va[j] = p[j];
        } else {
            #pragma unroll
            for (int j = 0; j < 4; j++) va[j] = bzero8();
        }
        {
            const bf16x8* p = (const bf16x8*)(Bt + (size_t)gn * K + k0 + (khalf << 5));
            #pragma unroll
            for (int j = 0; j < 4; j++) vb[j] = p[j];
        }
        __syncthreads();  // previous iteration's fragment reads complete
        #pragma unroll
        for (int j = 0; j < 4; j++) {
            *(bf16x8*)(As + r * 64 + wsl[j]) = va[j];
            *(bf16x8*)(Bs + r * 64 + wsl[j]) = vb[j];
        }
        __syncthreads();
        bf16x8 af[4][2], bfr[4][2];
        #pragma unroll
        for (int mi = 0; mi < 4; mi++) {
            const __hip_bfloat16* rp = As + (wm + mi * 16 + l16) * 64;
            af[mi][0] = *(const bf16x8*)(rp + rs0);
            af[mi][1] = *(const bf16x8*)(rp + rs1);
        }
        #pragma unroll
        for (int ni = 0; ni < 4; ni++) {
            const __hip_bfloat16* rp = Bs + (wn + ni * 16 + l16) * 64;
            bfr[ni][0] = *(const bf16x8*)(rp + rs0);
            bfr[ni][1] = *(const bf16x8*)(rp + rs1);
        }
        #pragma unroll
        for (int ks = 0; ks < 2; ks++)
            #pragma unroll
            for (int mi = 0; mi < 4; mi++)
                #pragma unroll
                for (int ni = 0; ni < 4; ni++)
                    acc[mi][ni] = __builtin_amdgcn_mfma_f32_16x16x32_bf16(
                        af[mi][ks], bfr[ni][ks], acc[mi][ni], 0, 0, 0);
    }

    #pragma unroll
    for (int mi = 0; mi < 4; mi++) {
        #pragma unroll
        for (int rr = 0; rr < 4; rr++) {
            int grow = bm0 + wm + mi * 16 + q * 4 + rr;
            if (grow >= Mrows) continue;
            size_t obase = (size_t)grow * N;
            #pragma unroll
            for (int ni = 0; ni < 4; ni++) {
                int col = bn0 + wn + ni * 16 + l16;
                float v = acc[mi][ni][rr];
                if (bias) v += bias[col];
                if (resid) v += resid[obase + col];
                if (flags & GF_RELU) v = fmaxf(v, 0.f);
                if (flags & GF_OUTBF16)
                    Cb[obase + col] = __float2bfloat16(v);
                else
                    Cf[obase + col] = v;
            }
        }
    }
}

// ---------------------------------------------------------------------------
// gemm64: 64(M)x128(N)xBK64 for qkv. 256 threads = 4 waves, each wave
// 64x32 (acc[4][2]). Register staging + both-sides XOR slot swizzle.
// ---------------------------------------------------------------------------
__global__ __launch_bounds__(256, 6) void gemm64(
    const __hip_bfloat16* __restrict__ A, const __hip_bfloat16* __restrict__ Bt,
    const float* __restrict__ bias, const float* __restrict__ resid,
    float* __restrict__ Cf, __hip_bfloat16* __restrict__ Cb,
    int Mrows, int N, int K, int flags, int gridN) {
    __shared__ __hip_bfloat16 As[64 * 64];
    __shared__ __hip_bfloat16 Bs[128 * 64];
    const int lin = xcd_remap(blockIdx.x, gridDim.x);
    const int bx = lin / gridN;           // A-major
    const int by = lin - bx * gridN;
    const int bm0 = bx << 6, bn0 = by << 7;

    const int tid = threadIdx.x;
    const int ra = tid >> 2, kq = tid & 3;      // A: 4 threads/row, 2 slots
    const int rb = tid >> 1, khalf = tid & 1;   // B: 2 threads/row, 4 slots
    const int lane = tid & 63;
    const int w = tid >> 6;
    const int wn = w << 5;                      // wave col offset 0/32/64/96
    const int q = lane >> 4;
    const int l16 = lane & 15;

    const int gra = bm0 + ra;
    const int gnb = bn0 + rb;

    int wslA[2];
    #pragma unroll
    for (int j = 0; j < 2; j++)
        wslA[j] = ((((kq << 1) | j) ^ (ra & 7)) << 3);
    int wslB[4];
    #pragma unroll
    for (int j = 0; j < 4; j++)
        wslB[j] = ((((khalf << 2) | j) ^ (rb & 7)) << 3);
    const int rs0 = ((q ^ (l16 & 7)) << 3);
    const int rs1 = (((4 + q) ^ (l16 & 7)) << 3);

    const size_t abase = (size_t)gra * K;

    f32x4 acc[4][2];
    #pragma unroll
    for (int i = 0; i < 4; i++)
        #pragma unroll
        for (int j = 0; j < 2; j++) {
            f32x4 z = {0.f, 0.f, 0.f, 0.f};
            acc[i][j] = z;
        }

    for (int k0 = 0; k0 < K; k0 += 64) {
        bf16x8 va[2], vb[4];
        if (gra < Mrows) {
            const bf16x8* p = (const bf16x8*)(A + abase + k0 + (kq << 4));
            #pragma unroll
            for (int j = 0; j < 2; j++) va[j] = p[j];
        } else {
            #pragma unroll
            for (int j = 0; j < 2; j++) va[j] = bzero8();
        }
        {
            const bf16x8* p = (const bf16x8*)(Bt + (size_t)gnb * K + k0 + (khalf << 5));
            #pragma unroll
            for (int j = 0; j < 4; j++) vb[j] = p[j];
        }
        __syncthreads();  // previous iteration's fragment reads complete
        #pragma unroll
        for (int j = 0; j < 2; j++)
            *(bf16x8*)(As + ra * 64 + wslA[j]) = va[j];
        #pragma unroll
        for (int j = 0; j < 4; j++)
            *(bf16x8*)(Bs + rb * 64 + wslB[j]) = vb[j];
        __syncthreads();
        bf16x8 af[4][2], bfr[2][2];
        #pragma unroll
        for (int mi = 0; mi < 4; mi++) {
            const __hip_bfloat16* rp = As + (mi * 16 + l16) * 64;
            af[mi][0] = *(const bf16x8*)(rp + rs0);
            af[mi][1] = *(const bf16x8*)(rp + rs1);
        }
        #pragma unroll
        for (int ni = 0; ni < 2; ni++) {
            const __hip_bfloat16* rp = Bs + (wn + ni * 16 + l16) * 64;
            bfr[ni][0] = *(const bf16x8*)(rp + rs0);
            bfr[ni][1] = *(const bf16x8*)(rp + rs1);
        }
        #pragma unroll
        for (int ks = 0; ks < 2; ks++)
            #pragma unroll
            for (int mi = 0; mi < 4; mi++)
                #pragma unroll
                for (int ni = 0; ni < 2; ni++)
                    acc[mi][ni] = __builtin_amdgcn_mfma_f32_16x16x32_bf16(
                        af[mi][ks], bfr[ni][ks], acc[mi][ni], 0, 0, 0);
    }

    #pragma unroll
    for (int mi = 0; mi < 4; mi++) {
        #pragma unroll
        for (int rr = 0; rr < 4; rr++) {
            int grow = bm0 + mi * 16 + q * 4 + rr;
            if (grow >= Mrows) continue;
            size_t obase = (size_t)grow * N;
            #pragma unroll
            for (int ni = 0; ni < 2; ni++) {
                int col = bn0 + wn + ni * 16 + l16;
                float v = acc[mi][ni][rr];
                if (bias) v += bias[col];
                if (resid) v += resid[obase + col];
                if (flags & GF_RELU) v = fmaxf(v, 0.f);
                if (flags & GF_OUTBF16)
                    Cb[obase + col] = __float2bfloat16(v);
                else
                    Cf[obase + col] = v;
            }
        }
    }
}

// ---------------------------------------------------------------------------
// R17 gemm32: 32(M)x128(N)xBK64 for the narrow N=512 GEMMs (proj, w2).
// 256 threads = 4 waves, each wave 32x32 (acc[2][2] = 16 AGPR). LDS 20KB
// (As 4KB + Bs 16KB) -> 8 blocks/CU = 32 waves/CU (hw max). A staging:
// 8 thr/row x 8 elems (1 slot); B staging identical to gemm64. Same XOR
// swizzle both sides. Grid 2728 for M=21824 (= 32*682 exact).
// ---------------------------------------------------------------------------
__global__ __launch_bounds__(256, 8) void gemm32(
    const __hip_bfloat16* __restrict__ A, const __hip_bfloat16* __restrict__ Bt,
    const float* __restrict__ bias, const float* __restrict__ resid,
    float* __restrict__ Cf, __hip_bfloat16* __restrict__ Cb,
    int Mrows, int N, int K, int flags, int gridN) {
    __shared__ __hip_bfloat16 As[32 * 64];
    __shared__ __hip_bfloat16 Bs[128 * 64];
    const int lin = xcd_remap(blockIdx.x, gridDim.x);
    const int bx = lin / gridN;           // A-major
    const int by = lin - bx * gridN;
    const int bm0 = bx << 5, bn0 = by << 7;

    const int tid = threadIdx.x;
    const int ra = tid >> 3, ca = tid & 7;      // A: 8 threads/row, 1 slot
    const int rb = tid >> 1, khalf = tid & 1;   // B: 2 threads/row, 4 slots
    const int lane = tid & 63;
    const int w = tid >> 6;
    const int wn = w << 5;                      // wave col offset 0/32/64/96
    const int q = lane >> 4;
    const int l16 = lane & 15;

    const int gra = bm0 + ra;
    const int gnb = bn0 + rb;

    const int wslA = ((ca ^ (ra & 7)) << 3);
    int wslB[4];
    #pragma unroll
    for (int j = 0; j < 4; j++)
        wslB[j] = ((((khalf << 2) | j) ^ (rb & 7)) << 3);
    const int rs0 = ((q ^ (l16 & 7)) << 3);
    const int rs1 = (((4 + q) ^ (l16 & 7)) << 3);

    const size_t abase = (size_t)gra * K;

    f32x4 acc[2][2];
    #pragma unroll
    for (int i = 0; i < 2; i++)
        #pragma unroll
        for (int j = 0; j < 2; j++) {
            f32x4 z = {0.f, 0.f, 0.f, 0.f};
            acc[i][j] = z;
        }

    for (int k0 = 0; k0 < K; k0 += 64) {
        bf16x8 va, vb[4];
        if (gra < Mrows)
            va = *(const bf16x8*)(A + abase + k0 + (ca << 3));
        else
            va = bzero8();
        {
            const bf16x8* p = (const bf16x8*)(Bt + (size_t)gnb * K + k0 + (khalf << 5));
            #pragma unroll
            for (int j = 0; j < 4; j++) vb[j] = p[j];
        }
        __syncthreads();  // previous iteration's fragment reads complete
        *(bf16x8*)(As + ra * 64 + wslA) = va;
        #pragma unroll
        for (int j = 0; j < 4; j++)
            *(bf16x8*)(Bs + rb * 64 + wslB[j]) = vb[j];
        __syncthreads();
        bf16x8 af[2][2], bfr[2][2];
        #pragma unroll
        for (int mi = 0; mi < 2; mi++) {
            const __hip_bfloat16* rp = As + (mi * 16 + l16) * 64;
            af[mi][0] = *(const bf16x8*)(rp + rs0);
            af[mi][1] = *(const bf16x8*)(rp + rs1);
        }
        #pragma unroll
        for (int ni = 0; ni < 2; ni++) {
            const __hip_bfloat16* rp = Bs + (wn + ni * 16 + l16) * 64;
            bfr[ni][0] = *(const bf16x8*)(rp + rs0);
            bfr[ni][1] = *(const bf16x8*)(rp + rs1);
        }
        #pragma unroll
        for (int ks = 0; ks < 2; ks++)
            #pragma unroll
            for (int mi = 0; mi < 2; mi++)
                #pragma unroll
                for (int ni = 0; ni < 2; ni++)
                    acc[mi][ni] = __builtin_amdgcn_mfma_f32_16x16x32_bf16(
                        af[mi][ks], bfr[ni][ks], acc[mi][ni], 0, 0, 0);
    }

    #pragma unroll
    for (int mi = 0; mi < 2; mi++) {
        #pragma unroll
        for (int rr = 0; rr < 4; rr++) {
            int grow = bm0 + mi * 16 + q * 4 + rr;
            if (grow >= Mrows) continue;
            size_t obase = (size_t)grow * N;
            #pragma unroll
            for (int ni = 0; ni < 2; ni++) {
                int col = bn0 + wn + ni * 16 + l16;
                float v = acc[mi][ni][rr];
                if (bias) v += bias[col];
                if (resid) v += resid[obase + col];
                if (flags & GF_RELU) v = fmaxf(v, 0.f);
                if (flags & GF_OUTBF16)
                    Cb[obase + col] = __float2bfloat16(v);
                else
                    Cf[obase + col] = v;
            }
        }
    }
}

// ---------------------------------------------------------------------------
// Fused branch-MLP GEMM (R8-R12 proven): all 5 source-depth levels in ONE
// 3664-block dispatch at 128^2 tiles.
// ---------------------------------------------------------------------------
__global__ __launch_bounds__(256) void gemm_branch_fused(
    const __hip_bfloat16* __restrict__ xn, const __hip_bfloat16* __restrict__ wcat,
    __hip_bfloat16* __restrict__ Y) {
    __shared__ __hip_bfloat16 As[128 * 64];
    __shared__ __hip_bfloat16 Bs[128 * 64];
    const int lin = xcd_remap(blockIdx.x, gridDim.x);
    int s;
    if (lin < 80)        s = 0;
    else if (lin < 208)  s = 1;
    else if (lin < 592)  s = 2;
    else if (lin < 1616) s = 3;
    else                 s = 4;
    const int base_tab[5] = {0, 80, 208, 592, 1616};
    const int gn_tab[5]   = {80, 64, 48, 32, 16};
    const size_t yoff[5]  = {0, 655360, 2752512, 9043968, 25821184};
    const int wcat_off[5] = {0, 5, 9, 12, 14};
    const int loc = lin - base_tab[s];
    const int gn = gn_tab[s];
    const int bx = loc / gn;              // A-major within each s
    const int by = loc - bx * gn;
    const int Mrows = 64 << (s << 1);
    const int N = (5 - s) << 11;
    gemm128_body<true>(As, Bs, xn, wcat + (size_t)wcat_off[s] * (2048ull * 512),
                       nullptr, nullptr, nullptr, Y + yoff[s],
                       Mrows, N, 512, GF_OUTBF16, s, bx << 7, by << 7);
}

// ---------------------------------------------------------------------------
// Combine: h[b,node@d,:] = ReLU( sum_{s<=d} Y_s[...] + b1[node] ).
// R15: XCD-chunked remap (same-batch rows share ancestor Y segments).
// ---------------------------------------------------------------------------
__global__ __launch_bounds__(256) void combine_kernel(const __hip_bfloat16* __restrict__ Y,
                                                      const float* __restrict__ b1,
                                                      __hip_bfloat16* __restrict__ h) {
    const size_t yoff[5] = {0, 655360, 2752512, 9043968, 25821184};
    int row = xcd_remap(blockIdx.x, gridDim.x);
    int b = row / 341;
    int node = row - b * 341;
    int d = (node >= 85) ? 4 : (node >= 21) ? 3 : (node >= 5) ? 2 : (node >= 1) ? 1 : 0;
    int i = node - (0x55555555 & ((1 << (d << 1)) - 1));
    int j = threadIdx.x << 3;

    float acc[8];
    const float* bp = b1 + (size_t)node * 2048 + j;
    f32x4 b0 = *(const f32x4*)bp;
    f32x4 b4 = *(const f32x4*)(bp + 4);
    #pragma unroll
    for (int u = 0; u < 4; u++) { acc[u] = b0[u]; acc[u + 4] = b4[u]; }

    #pragma unroll
    for (int s = 0; s < 5; s++) {
        if (s <= d) {
            int a = i >> ((d - s) << 1);
            int width = (5 - s) << 11;
            const bf16x8 v = *(const bf16x8*)(Y + yoff[s] +
                (size_t)((b << (s << 1)) + a) * width + ((d - s) << 11) + j);
            #pragma unroll
            for (int u = 0; u < 8; u++) acc[u] += (float)v[u];
        }
    }
    bf16x8 o;
    #pragma unroll
    for (int u = 0; u < 8; u++) o[u] = (__bf16)fmaxf(acc[u], 0.f);
    *(bf16x8*)(h + (size_t)row * 2048 + j) = o;
}

// ---------------------------------------------------------------------------
extern "C" void kernel_launch(void* const* d_in, const int* in_sizes, int n_in,
                              void* d_out, int out_size, void* d_ws, size_t ws_size,
                              hipStream_t stream) {
    const float* x      = (const float*)d_in[0];
    const float* ln1_g  = (const float*)d_in[1];
    const float* ln1_b  = (const float*)d_in[2];
    const float* w_qkv  = (const float*)d_in[3];
    const float* b_qkv  = (const float*)d_in[4];
    const float* w_proj = (const float*)d_in[5];
    const float* b_proj = (const float*)d_in[6];
    const float* ln2_g  = (const float*)d_in[7];
    const float* ln2_b  = (const float*)d_in[8];
    const float* mlp_M  = (const float*)d_in[9];
    const float* mlp_b1 = (const float*)d_in[10];
    const float* w2     = (const float*)d_in[11];
    const float* b2     = (const float*)d_in[12];
    float* out = (float*)d_out;

    const int M = 64 * 341;  // 21824 rows

    char* ws = (char*)d_ws;
    size_t off = 0;
    auto alloc = [&](size_t bytes) -> char* {
        char* p = ws + off;
        off += (bytes + 255) & ~(size_t)255;
        return p;
    };
    __hip_bfloat16* xn     = (__hip_bfloat16*)alloc((size_t)M * 512 * 2);
    __hip_bfloat16* wqkvT  = (__hip_bfloat16*)alloc(1536ull * 512 * 2);
    __hip_bfloat16* wprojT = (__hip_bfloat16*)alloc(512ull * 512 * 2);
    __hip_bfloat16* w2T    = (__hip_bfloat16*)alloc(512ull * 2048 * 2);
    __hip_bfloat16* wcat   = (__hip_bfloat16*)alloc(15ull * 2048 * 512 * 2);
    __hip_bfloat16* hbuf   = (__hip_bfloat16*)alloc((size_t)M * 2048 * 2);
    // shared region: qkv+ctx (attention phase) overlaid by Y (branch phase)
    const size_t qkv_bytes = (size_t)M * 1536 * 2;            // 67,043,328
    const size_t y_bytes   = 59375616ull * 2;                 // 118,751,232
    char* shared = alloc(y_bytes);                            // >= qkv+ctx
    __hip_bfloat16* qkv = (__hip_bfloat16*)shared;
    __hip_bfloat16* ctx = (__hip_bfloat16*)(shared + qkv_bytes);
    __hip_bfloat16* Y   = (__hip_bfloat16*)shared;
    if (off > ws_size) return;  // workspace too small -> clean validation failure

    auto g64 = [&](const __hip_bfloat16* A, const __hip_bfloat16* Bt,
                   const float* bias, const float* resid, float* Cf,
                   __hip_bfloat16* Cb, int Mr, int N, int K, int flags) {
        int gm = (Mr + 63) >> 6, gn = N >> 7;
        gemm64<<<dim3(gm * gn), 256, 0, stream>>>(
            A, Bt, bias, resid, Cf, Cb, Mr, N, K, flags, gn);
    };
    auto g32 = [&](const __hip_bfloat16* A, const __hip_bfloat16* Bt,
                   const float* bias, const float* resid, float* Cf,
                   __hip_bfloat16* Cb, int Mr, int N, int K, int flags) {
        int gm = (Mr + 31) >> 5, gn = N >> 7;
        gemm32<<<dim3(gm * gn), 256, 0, stream>>>(
            A, Bt, bias, resid, Cf, Cb, Mr, N, K, flags, gn);
    };

    // fused weight prep (one dispatch)
    prep_kernel<<<dim3(17408), 256, 0, stream>>>(w_qkv, w_proj, w2, mlp_M,
                                                 wqkvT, wprojT, w2T, wcat);

    // attention path (qkv on gemm64; proj on gemm32)
    ln_kernel<<<M, 256, 0, stream>>>(x, ln1_g, ln1_b, xn);
    g64(xn, wqkvT, b_qkv, nullptr, nullptr, qkv, M, 1536, 512, GF_OUTBF16);
    attn_mfma_kernel<<<dim3(512, 2), 256, 0, stream>>>(qkv, ctx);
    g32(ctx, wprojT, b_proj, x, out, nullptr, M, 512, 512, 0);

    // branch MLP path (dedup by source depth s) — single fused dispatch
    ln_kernel<<<M, 256, 0, stream>>>(out, ln2_g, ln2_b, xn);
    gemm_branch_fused<<<dim3(3664), 256, 0, stream>>>(xn, wcat, Y);
    combine_kernel<<<M, 256, 0, stream>>>(Y, mlp_b1, hbuf);
    g32(hbuf, w2T, b2, out, out, nullptr, M, 512, 2048, 0);
}

// Round 13
// 688.681 us; speedup vs baseline: 1.0264x; 1.0264x over previous
//
#include <hip/hip_runtime.h>
#include <hip/hip_bf16.h>

// ---------------------------------------------------------------------------
// Treensformer block: x += MHSA(LN1(x)); x += BranchMLP(LN2(x))
// B=64, N_NODES=341, E=512, H=8, hd=64, 4*E=2048, N_LEVELS=4
// R1: MFMA flash attention. R5: branch-MLP ancestor dedup.
// R6/R7: 256^2 deep pipeline -> REGRESSED. R8: 128^2 + fused branch +
//     XCD/A-major remap: 785us. R9: BK64 + XOR swizzle: 751 (conflicts->0).
// R10: gemm64 for proj/w2: 722 (occupancy 23->45%). R11: split-K: REGRESS.
// R12: ~neutral. R13: gemm64 qkv(-6 WIN) + branch(+26 REGRESS).
// R14: combine-into-w2 staging fusion: REGRESSED HARD.
// R15: best-of-each assembly: 702. WIN. R16: exp2-softmax + LN vec +
//     fused prep: 691. WIN (best).
// R17: gemm32 (32x128) for proj/w2: REGRESSED (w2 125->145 despite occ
//     44->70%). Mechanism error exposed: the per-block serial chain is
//     the K-LOOP (32 iters for w2) - independent of tile M. Halving M
//     halved MFMA/iter but not chain length; grid rounds 0.9 -> 1.3 ->
//     wall x1.16. Once a grid is fully co-resident, wall ~= one block's
//     chain; more blocks or block-split-K (rounds x2, chain /2) net zero.
//     GEMM plateau DECLARED: 2-barrier gemm64 at full residency is this
//     decomposition's fixed point (w2 ~121us, 15% MFMA, 13% HBM).
// R18: restore measured-best R16 configuration (691us).
// ---------------------------------------------------------------------------

typedef __attribute__((ext_vector_type(8))) __bf16 bf16x8;
typedef __attribute__((ext_vector_type(4))) __bf16 bf16x4;
typedef __attribute__((ext_vector_type(2))) __bf16 bf16x2;
typedef __attribute__((ext_vector_type(4))) float f32x4;
typedef __attribute__((ext_vector_type(2))) float f32x2;
typedef __attribute__((ext_vector_type(4))) unsigned int u32x4;

#define GF_RELU    1
#define GF_OUTBF16 2

static __device__ __forceinline__ bf16x8 bzero8() {
    u32x4 z = {0u, 0u, 0u, 0u};
    return __builtin_bit_cast(bf16x8, z);
}

// ---------------------------------------------------------------------------
// R16 fused prep kernel: all weight prep in ONE dispatch, 4 elems/thread.
// ---------------------------------------------------------------------------
__global__ __launch_bounds__(256) void prep_kernel(
    const float* __restrict__ w_qkv, const float* __restrict__ w_proj,
    const float* __restrict__ w2, const float* __restrict__ M,
    __hip_bfloat16* __restrict__ wqkvT, __hip_bfloat16* __restrict__ wprojT,
    __hip_bfloat16* __restrict__ w2T, __hip_bfloat16* __restrict__ wcat) {
    const int bid = blockIdx.x;
    if (bid < 2048) {
        // transpose jobs
        const float* in;
        __hip_bfloat16* out;
        int N, log2K, loc;
        if (bid < 768)       { in = w_qkv;  out = wqkvT;  N = 1536; log2K = 9;  loc = bid; }
        else if (bid < 1024) { in = w_proj; out = wprojT; N = 512;  log2K = 9;  loc = bid - 768; }
        else                 { in = w2;     out = w2T;    N = 512;  log2K = 11; loc = bid - 1024; }
        int idx4 = (loc * 256 + threadIdx.x) << 2;
        int n = idx4 >> log2K;
        int k = idx4 & ((1 << log2K) - 1);
        bf16x4 o;
        #pragma unroll
        for (int u = 0; u < 4; u++)
            o[u] = (__bf16)__float2bfloat16(in[(size_t)(k + u) * N + n]);
        *(bf16x4*)(out + idx4) = o;
    } else {
        // pack_wcat: 15 (s,d) pairs x 1024 blocks each
        int loc = bid - 2048;
        int p = loc >> 10;          // 0..14
        int blk = loc & 1023;
        int s, d;
        if (p < 5)       { s = 0; d = p; }
        else if (p < 9)  { s = 1; d = p - 4; }
        else if (p < 12) { s = 2; d = p - 7; }
        else if (p < 14) { s = 3; d = p - 9; }
        else             { s = 4; d = 4; }
        const int base_lut[5] = {0, 5, 9, 12, 14};
        size_t idx4 = ((size_t)blk * 256 + threadIdx.x) << 2;
        const size_t MB = 2048ull * 512;
        f32x4 v = *(const f32x4*)(M + ((size_t)d * 5 + s) * MB + idx4);
        bf16x4 o;
        #pragma unroll
        for (int u = 0; u < 4; u++) o[u] = (__bf16)__float2bfloat16(v[u]);
        *(bf16x4*)(wcat + (size_t)base_lut[s] * MB + (size_t)(d - s) * MB + idx4) = o;
    }
}

// ---------------------------------------------------------------------------
// LayerNorm over E=512, one block (256 threads) per token; float2 loads,
// bf16x2 stores (R16 vectorization).
// ---------------------------------------------------------------------------
__global__ __launch_bounds__(256) void ln_kernel(const float* __restrict__ x,
                                                 const float* __restrict__ g,
                                                 const float* __restrict__ b,
                                                 __hip_bfloat16* __restrict__ out) {
    int tok = blockIdx.x;
    const float* xr = x + (size_t)tok * 512;
    int t = threadIdx.x;
    f32x2 v = *(const f32x2*)(xr + 2 * t);
    float s = v[0] + v[1];
    float s2 = v[0] * v[0] + v[1] * v[1];
    #pragma unroll
    for (int o = 32; o > 0; o >>= 1) {
        s  += __shfl_down(s, o);
        s2 += __shfl_down(s2, o);
    }
    __shared__ float ps[4], ps2[4];
    int w = t >> 6, lane = t & 63;
    if (lane == 0) { ps[w] = s; ps2[w] = s2; }
    __syncthreads();
    if (t == 0) {
        float ts = 0.f, ts2 = 0.f;
        #pragma unroll
        for (int i = 0; i < 4; i++) { ts += ps[i]; ts2 += ps2[i]; }
        ps[0] = ts * (1.f / 512.f);
        ps2[0] = ts2 * (1.f / 512.f);
    }
    __syncthreads();
    float m = ps[0];
    float var = ps2[0] - m * m;
    float r = rsqrtf(var + 1e-5f);
    f32x2 gv = *(const f32x2*)(g + 2 * t);
    f32x2 bv = *(const f32x2*)(b + 2 * t);
    bf16x2 o;
    o[0] = (__bf16)__float2bfloat16((v[0] - m) * r * gv[0] + bv[0]);
    o[1] = (__bf16)__float2bfloat16((v[1] - m) * r * gv[1] + bv[1]);
    *(bf16x2*)(out + (size_t)tok * 512 + 2 * t) = o;
}

// ---------------------------------------------------------------------------
// MFMA flash attention (R16: exp2-domain online softmax).
// ---------------------------------------------------------------------------
#define ATT_STR 72
#define SC2 0.18033688f   // 0.125 * log2(e)
__global__ __launch_bounds__(256) void attn_mfma_kernel(const __hip_bfloat16* __restrict__ qkv,
                                                        __hip_bfloat16* __restrict__ ctx) {
    __shared__ __bf16 kt_lds[64 * ATT_STR];
    __shared__ __bf16 vt_lds[64 * ATT_STR];
    __shared__ __bf16 pbuf[4 * 48 * ATT_STR];

    const int bh = blockIdx.x;
    const int half = blockIdx.y;
    const int b = bh >> 3, h = bh & 7;
    const int tid = threadIdx.x;
    const int w = tid >> 6, lane = tid & 63;
    const int q = lane >> 4, l16 = lane & 15;
    const int rowbase = half * 192 + w * 48;
    __bf16* pw = pbuf + w * 48 * ATT_STR;

    bf16x8 qf[3][2];
    #pragma unroll
    for (int mi = 0; mi < 3; mi++) {
        int row = rowbase + mi * 16 + l16;
        #pragma unroll
        for (int ks = 0; ks < 2; ks++) {
            if (row < 341)
                qf[mi][ks] = *(const bf16x8*)(qkv + (size_t)(b * 341 + row) * 1536 +
                                              h * 64 + ks * 32 + q * 8);
            else
                qf[mi][ks] = bzero8();
        }
    }

    f32x4 O[3][4];
    float mrun[3][4], lrun[3][4];
    #pragma unroll
    for (int mi = 0; mi < 3; mi++) {
        #pragma unroll
        for (int ni = 0; ni < 4; ni++) { f32x4 z = {0.f,0.f,0.f,0.f}; O[mi][ni] = z; }
        #pragma unroll
        for (int rr = 0; rr < 4; rr++) { mrun[mi][rr] = -1e30f; lrun[mi][rr] = 0.f; }
    }

    for (int kt6 = 0; kt6 < 6; kt6++) {
        const int kbase = kt6 * 64;
        __syncthreads();
        {
            int key = tid >> 2, kg = tid & 3;
            int gk = kbase + key;
            bf16x8 a0 = bzero8(), a1 = bzero8();
            if (gk < 341) {
                const __hip_bfloat16* src =
                    qkv + (size_t)(b * 341 + gk) * 1536 + 512 + h * 64 + kg * 16;
                a0 = *(const bf16x8*)src;
                a1 = *(const bf16x8*)(src + 8);
            }
            *(bf16x8*)(kt_lds + key * ATT_STR + kg * 16)     = a0;
            *(bf16x8*)(kt_lds + key * ATT_STR + kg * 16 + 8) = a1;
        }
        {
            int key = tid & 63, dg = tid >> 6;
            int gk = kbase + key;
            bf16x8 a0 = bzero8(), a1 = bzero8();
            if (gk < 341) {
                const __hip_bfloat16* src =
                    qkv + (size_t)(b * 341 + gk) * 1536 + 1024 + h * 64 + dg * 16;
                a0 = *(const bf16x8*)src;
                a1 = *(const bf16x8*)(src + 8);
            }
            #pragma unroll
            for (int j = 0; j < 8; j++) {
                vt_lds[(dg * 16 + j) * ATT_STR + key]     = a0[j];
                vt_lds[(dg * 16 + 8 + j) * ATT_STR + key] = a1[j];
            }
        }
        __syncthreads();

        f32x4 S[3][4];
        #pragma unroll
        for (int mi = 0; mi < 3; mi++)
            #pragma unroll
            for (int ni = 0; ni < 4; ni++) { f32x4 z = {0.f,0.f,0.f,0.f}; S[mi][ni] = z; }
        #pragma unroll
        for (int ks = 0; ks < 2; ks++) {
            bf16x8 bf_[4];
            #pragma unroll
            for (int ni = 0; ni < 4; ni++)
                bf_[ni] = *(const bf16x8*)(kt_lds + (ni * 16 + l16) * ATT_STR + ks * 32 + q * 8);
            #pragma unroll
            for (int mi = 0; mi < 3; mi++)
                #pragma unroll
                for (int ni = 0; ni < 4; ni++)
                    S[mi][ni] = __builtin_amdgcn_mfma_f32_16x16x32_bf16(qf[mi][ks], bf_[ni],
                                                                        S[mi][ni], 0, 0, 0);
        }

        float cmask[4];
        #pragma unroll
        for (int ni = 0; ni < 4; ni++)
            cmask[ni] = (kbase + ni * 16 + l16 < 341) ? 0.f : -1e30f;

        #pragma unroll
        for (int mi = 0; mi < 3; mi++) {
            #pragma unroll
            for (int rr = 0; rr < 4; rr++) {
                float rmax = -1e30f;
                #pragma unroll
                for (int ni = 0; ni < 4; ni++)
                    rmax = fmaxf(rmax, fmaf(S[mi][ni][rr], SC2, cmask[ni]));
                rmax = fmaxf(rmax, __shfl_xor(rmax, 1));
                rmax = fmaxf(rmax, __shfl_xor(rmax, 2));
                rmax = fmaxf(rmax, __shfl_xor(rmax, 4));
                rmax = fmaxf(rmax, __shfl_xor(rmax, 8));
                float mnew = fmaxf(mrun[mi][rr], rmax);
                float alpha = exp2f(mrun[mi][rr] - mnew);
                mrun[mi][rr] = mnew;
                float psum = 0.f;
                #pragma unroll
                for (int ni = 0; ni < 4; ni++) {
                    float p = exp2f(fmaf(S[mi][ni][rr], SC2, cmask[ni]) - mnew);
                    S[mi][ni][rr] = p;
                    psum += p;
                    O[mi][ni][rr] *= alpha;
                }
                psum += __shfl_xor(psum, 1);
                psum += __shfl_xor(psum, 2);
                psum += __shfl_xor(psum, 4);
                psum += __shfl_xor(psum, 8);
                lrun[mi][rr] = lrun[mi][rr] * alpha + psum;
            }
            #pragma unroll
            for (int ni = 0; ni < 4; ni++)
                #pragma unroll
                for (int rr = 0; rr < 4; rr++)
                    pw[(mi * 16 + q * 4 + rr) * ATT_STR + ni * 16 + l16] =
                        (__bf16)S[mi][ni][rr];
        }
        __syncthreads();

        #pragma unroll
        for (int ks = 0; ks < 2; ks++) {
            bf16x8 pf[3], vf[4];
            #pragma unroll
            for (int mi = 0; mi < 3; mi++)
                pf[mi] = *(const bf16x8*)(pw + (mi * 16 + l16) * ATT_STR + ks * 32 + q * 8);
            #pragma unroll
            for (int ni = 0; ni < 4; ni++)
                vf[ni] = *(const bf16x8*)(vt_lds + (ni * 16 + l16) * ATT_STR + ks * 32 + q * 8);
            #pragma unroll
            for (int mi = 0; mi < 3; mi++)
                #pragma unroll
                for (int ni = 0; ni < 4; ni++)
                    O[mi][ni] = __builtin_amdgcn_mfma_f32_16x16x32_bf16(pf[mi], vf[ni],
                                                                        O[mi][ni], 0, 0, 0);
        }
    }

    #pragma unroll
    for (int mi = 0; mi < 3; mi++) {
        #pragma unroll
        for (int rr = 0; rr < 4; rr++) {
            int row = rowbase + mi * 16 + q * 4 + rr;
            if (row >= 341) continue;
            float inv = 1.f / lrun[mi][rr];
            __hip_bfloat16* op = ctx + (size_t)(b * 341 + row) * 512 + h * 64;
            #pragma unroll
            for (int ni = 0; ni < 4; ni++)
                op[ni * 16 + l16] = __float2bfloat16(O[mi][ni][rr] * inv);
        }
    }
}

// bijective XCD-aware remap (m204): each XCD gets a contiguous chunk of the
// logical (A-major) tile order -> neighboring tiles sharing an A row-panel
// land on the same XCD's L2.
static __device__ __forceinline__ int xcd_remap(int bid, int nwg) {
    const int xcd = bid & 7, o = bid >> 3;
    const int qq = nwg >> 3, rr = nwg & 7;
    return (xcd < rr ? xcd * (qq + 1) : rr * (qq + 1) + (xcd - rr) * qq) + o;
}

// ---------------------------------------------------------------------------
// gemm128 body (128x128xBK64, register staging, both-sides XOR swizzle).
// Used by the fused branch GEMM only (deep grid; R13 proved 64x128 hurts it).
// ---------------------------------------------------------------------------
template <bool GATHER>
static __device__ __forceinline__ void gemm128_body(
    __hip_bfloat16* As, __hip_bfloat16* Bs,
    const __hip_bfloat16* __restrict__ A, const __hip_bfloat16* __restrict__ Bt,
    const float* __restrict__ bias, const float* __restrict__ resid,
    float* __restrict__ Cf, __hip_bfloat16* __restrict__ Cb,
    int Mrows, int N, int K, int flags, int depth, int bm0, int bn0) {
    const int tid = threadIdx.x;
    const int r = tid >> 1;            // staging row 0..127
    const int khalf = tid & 1;         // 0/1 -> 32-element (64B) half of row
    const int gr = bm0 + r;
    const int gn = bn0 + r;
    const int lane = tid & 63;
    const int w = tid >> 6;
    const int wm = (w >> 1) << 6;
    const int wn = (w & 1) << 6;
    const int q = lane >> 4;
    const int l16 = lane & 15;

    int wsl[4];
    #pragma unroll
    for (int j = 0; j < 4; j++)
        wsl[j] = ((((khalf << 2) | j) ^ (r & 7)) << 3);
    const int rs0 = ((q ^ (l16 & 7)) << 3);
    const int rs1 = (((4 + q) ^ (l16 & 7)) << 3);

    size_t abase;
    if (GATHER) {
        const int dsh = depth << 1;
        const int bmask = (1 << dsh) - 1;
        int b = gr >> dsh;
        int i = gr & bmask;
        int node = (0x55555555 & bmask) + i;   // offs[depth] + i
        abase = ((size_t)(b * 341 + node)) << 9;
    } else {
        abase = (size_t)gr * K;
    }

    f32x4 acc[4][4];
    #pragma unroll
    for (int i = 0; i < 4; i++)
        #pragma unroll
        for (int j = 0; j < 4; j++) {
            f32x4 z = {0.f, 0.f, 0.f, 0.f};
            acc[i][j] = z;
        }

    for (int k0 = 0; k0 < K; k0 += 64) {
        bf16x8 va[4], vb[4];
        if (gr < Mrows) {
            const bf16x8* p = (const bf16x8*)(A + abase + k0 + (khalf << 5));
            #pragma unroll
            for (int j = 0; j < 4; j++) va[j] = p[j];
        } else {
            #pragma unroll
            for (int j = 0; j < 4; j++) va[j] = bzero8();
        }
        {
            const bf16x8* p = (const bf16x8*)(Bt + (size_t)gn * K + k0 + (khalf << 5));
            #pragma unroll
            for (int j = 0; j < 4; j++) vb[j] = p[j];
        }
        __syncthreads();  // previous iteration's fragment reads complete
        #pragma unroll
        for (int j = 0; j < 4; j++) {
            *(bf16x8*)(As + r * 64 + wsl[j]) = va[j];
            *(bf16x8*)(Bs + r * 64 + wsl[j]) = vb[j];
        }
        __syncthreads();
        bf16x8 af[4][2], bfr[4][2];
        #pragma unroll
        for (int mi = 0; mi < 4; mi++) {
            const __hip_bfloat16* rp = As + (wm + mi * 16 + l16) * 64;
            af[mi][0] = *(const bf16x8*)(rp + rs0);
            af[mi][1] = *(const bf16x8*)(rp + rs1);
        }
        #pragma unroll
        for (int ni = 0; ni < 4; ni++) {
            const __hip_bfloat16* rp = Bs + (wn + ni * 16 + l16) * 64;
            bfr[ni][0] = *(const bf16x8*)(rp + rs0);
            bfr[ni][1] = *(const bf16x8*)(rp + rs1);
        }
        #pragma unroll
        for (int ks = 0; ks < 2; ks++)
            #pragma unroll
            for (int mi = 0; mi < 4; mi++)
                #pragma unroll
                for (int ni = 0; ni < 4; ni++)
                    acc[mi][ni] = __builtin_amdgcn_mfma_f32_16x16x32_bf16(
                        af[mi][ks], bfr[ni][ks], acc[mi][ni], 0, 0, 0);
    }

    #pragma unroll
    for (int mi = 0; mi < 4; mi++) {
        #pragma unroll
        for (int rr = 0; rr < 4; rr++) {
            int grow = bm0 + wm + mi * 16 + q * 4 + rr;
            if (grow >= Mrows) continue;
            size_t obase = (size_t)grow * N;
            #pragma unroll
            for (int ni = 0; ni < 4; ni++) {
                int col = bn0 + wn + ni * 16 + l16;
                float v = acc[mi][ni][rr];
                if (bias) v += bias[col];
                if (resid) v += resid[obase + col];
                if (flags & GF_RELU) v = fmaxf(v, 0.f);
                if (flags & GF_OUTBF16)
                    Cb[obase + col] = __float2bfloat16(v);
                else
                    Cf[obase + col] = v;
            }
        }
    }
}

// ---------------------------------------------------------------------------
// gemm64: 64(M)x128(N)xBK64 for qkv, proj, w2. 256 threads = 4 waves, each
// wave 64x32 (acc[4][2] = 32 AGPR; ~72 unified regs -> 6 blocks/CU with
// 24KB LDS). Register staging + both-sides XOR slot swizzle (R9/R10).
// ---------------------------------------------------------------------------
__global__ __launch_bounds__(256, 6) void gemm64(
    const __hip_bfloat16* __restrict__ A, const __hip_bfloat16* __restrict__ Bt,
    const float* __restrict__ bias, const float* __restrict__ resid,
    float* __restrict__ Cf, __hip_bfloat16* __restrict__ Cb,
    int Mrows, int N, int K, int flags, int gridN) {
    __shared__ __hip_bfloat16 As[64 * 64];
    __shared__ __hip_bfloat16 Bs[128 * 64];
    const int lin = xcd_remap(blockIdx.x, gridDim.x);
    const int bx = lin / gridN;           // A-major
    const int by = lin - bx * gridN;
    const int bm0 = bx << 6, bn0 = by << 7;

    const int tid = threadIdx.x;
    const int ra = tid >> 2, kq = tid & 3;      // A: 4 threads/row, 2 slots
    const int rb = tid >> 1, khalf = tid & 1;   // B: 2 threads/row, 4 slots
    const int lane = tid & 63;
    const int w = tid >> 6;
    const int wn = w << 5;                      // wave col offset 0/32/64/96
    const int q = lane >> 4;
    const int l16 = lane & 15;

    const int gra = bm0 + ra;
    const int gnb = bn0 + rb;

    int wslA[2];
    #pragma unroll
    for (int j = 0; j < 2; j++)
        wslA[j] = ((((kq << 1) | j) ^ (ra & 7)) << 3);
    int wslB[4];
    #pragma unroll
    for (int j = 0; j < 4; j++)
        wslB[j] = ((((khalf << 2) | j) ^ (rb & 7)) << 3);
    const int rs0 = ((q ^ (l16 & 7)) << 3);
    const int rs1 = (((4 + q) ^ (l16 & 7)) << 3);

    const size_t abase = (size_t)gra * K;

    f32x4 acc[4][2];
    #pragma unroll
    for (int i = 0; i < 4; i++)
        #pragma unroll
        for (int j = 0; j < 2; j++) {
            f32x4 z = {0.f, 0.f, 0.f, 0.f};
            acc[i][j] = z;
        }

    for (int k0 = 0; k0 < K; k0 += 64) {
        bf16x8 va[2], vb[4];
        if (gra < Mrows) {
            const bf16x8* p = (const bf16x8*)(A + abase + k0 + (kq << 4));
            #pragma unroll
            for (int j = 0; j < 2; j++) va[j] = p[j];
        } else {
            #pragma unroll
            for (int j = 0; j < 2; j++) va[j] = bzero8();
        }
        {
            const bf16x8* p = (const bf16x8*)(Bt + (size_t)gnb * K + k0 + (khalf << 5));
            #pragma unroll
            for (int j = 0; j < 4; j++) vb[j] = p[j];
        }
        __syncthreads();  // previous iteration's fragment reads complete
        #pragma unroll
        for (int j = 0; j < 2; j++)
            *(bf16x8*)(As + ra * 64 + wslA[j]) = va[j];
        #pragma unroll
        for (int j = 0; j < 4; j++)
            *(bf16x8*)(Bs + rb * 64 + wslB[j]) = vb[j];
        __syncthreads();
        bf16x8 af[4][2], bfr[2][2];
        #pragma unroll
        for (int mi = 0; mi < 4; mi++) {
            const __hip_bfloat16* rp = As + (mi * 16 + l16) * 64;
            af[mi][0] = *(const bf16x8*)(rp + rs0);
            af[mi][1] = *(const bf16x8*)(rp + rs1);
        }
        #pragma unroll
        for (int ni = 0; ni < 2; ni++) {
            const __hip_bfloat16* rp = Bs + (wn + ni * 16 + l16) * 64;
            bfr[ni][0] = *(const bf16x8*)(rp + rs0);
            bfr[ni][1] = *(const bf16x8*)(rp + rs1);
        }
        #pragma unroll
        for (int ks = 0; ks < 2; ks++)
            #pragma unroll
            for (int mi = 0; mi < 4; mi++)
                #pragma unroll
                for (int ni = 0; ni < 2; ni++)
                    acc[mi][ni] = __builtin_amdgcn_mfma_f32_16x16x32_bf16(
                        af[mi][ks], bfr[ni][ks], acc[mi][ni], 0, 0, 0);
    }

    #pragma unroll
    for (int mi = 0; mi < 4; mi++) {
        #pragma unroll
        for (int rr = 0; rr < 4; rr++) {
            int grow = bm0 + mi * 16 + q * 4 + rr;
            if (grow >= Mrows) continue;
            size_t obase = (size_t)grow * N;
            #pragma unroll
            for (int ni = 0; ni < 2; ni++) {
                int col = bn0 + wn + ni * 16 + l16;
                float v = acc[mi][ni][rr];
                if (bias) v += bias[col];
                if (resid) v += resid[obase + col];
                if (flags & GF_RELU) v = fmaxf(v, 0.f);
                if (flags & GF_OUTBF16)
                    Cb[obase + col] = __float2bfloat16(v);
                else
                    Cf[obase + col] = v;
            }
        }
    }
}

// ---------------------------------------------------------------------------
// Fused branch-MLP GEMM (R8-R12 proven): all 5 source-depth levels in ONE
// 3664-block dispatch at 128^2 tiles.
// ---------------------------------------------------------------------------
__global__ __launch_bounds__(256) void gemm_branch_fused(
    const __hip_bfloat16* __restrict__ xn, const __hip_bfloat16* __restrict__ wcat,
    __hip_bfloat16* __restrict__ Y) {
    __shared__ __hip_bfloat16 As[128 * 64];
    __shared__ __hip_bfloat16 Bs[128 * 64];
    const int lin = xcd_remap(blockIdx.x, gridDim.x);
    int s;
    if (lin < 80)        s = 0;
    else if (lin < 208)  s = 1;
    else if (lin < 592)  s = 2;
    else if (lin < 1616) s = 3;
    else                 s = 4;
    const int base_tab[5] = {0, 80, 208, 592, 1616};
    const int gn_tab[5]   = {80, 64, 48, 32, 16};
    const size_t yoff[5]  = {0, 655360, 2752512, 9043968, 25821184};
    const int wcat_off[5] = {0, 5, 9, 12, 14};
    const int loc = lin - base_tab[s];
    const int gn = gn_tab[s];
    const int bx = loc / gn;              // A-major within each s
    const int by = loc - bx * gn;
    const int Mrows = 64 << (s << 1);
    const int N = (5 - s) << 11;
    gemm128_body<true>(As, Bs, xn, wcat + (size_t)wcat_off[s] * (2048ull * 512),
                       nullptr, nullptr, nullptr, Y + yoff[s],
                       Mrows, N, 512, GF_OUTBF16, s, bx << 7, by << 7);
}

// ---------------------------------------------------------------------------
// Combine: h[b,node@d,:] = ReLU( sum_{s<=d} Y_s[...] + b1[node] ).
// R15: XCD-chunked remap (same-batch rows share ancestor Y segments).
// ---------------------------------------------------------------------------
__global__ __launch_bounds__(256) void combine_kernel(const __hip_bfloat16* __restrict__ Y,
                                                      const float* __restrict__ b1,
                                                      __hip_bfloat16* __restrict__ h) {
    const size_t yoff[5] = {0, 655360, 2752512, 9043968, 25821184};
    int row = xcd_remap(blockIdx.x, gridDim.x);
    int b = row / 341;
    int node = row - b * 341;
    int d = (node >= 85) ? 4 : (node >= 21) ? 3 : (node >= 5) ? 2 : (node >= 1) ? 1 : 0;
    int i = node - (0x55555555 & ((1 << (d << 1)) - 1));
    int j = threadIdx.x << 3;

    float acc[8];
    const float* bp = b1 + (size_t)node * 2048 + j;
    f32x4 b0 = *(const f32x4*)bp;
    f32x4 b4 = *(const f32x4*)(bp + 4);
    #pragma unroll
    for (int u = 0; u < 4; u++) { acc[u] = b0[u]; acc[u + 4] = b4[u]; }

    #pragma unroll
    for (int s = 0; s < 5; s++) {
        if (s <= d) {
            int a = i >> ((d - s) << 1);
            int width = (5 - s) << 11;
            const bf16x8 v = *(const bf16x8*)(Y + yoff[s] +
                (size_t)((b << (s << 1)) + a) * width + ((d - s) << 11) + j);
            #pragma unroll
            for (int u = 0; u < 8; u++) acc[u] += (float)v[u];
        }
    }
    bf16x8 o;
    #pragma unroll
    for (int u = 0; u < 8; u++) o[u] = (__bf16)fmaxf(acc[u], 0.f);
    *(bf16x8*)(h + (size_t)row * 2048 + j) = o;
}

// ---------------------------------------------------------------------------
extern "C" void kernel_launch(void* const* d_in, const int* in_sizes, int n_in,
                              void* d_out, int out_size, void* d_ws, size_t ws_size,
                              hipStream_t stream) {
    const float* x      = (const float*)d_in[0];
    const float* ln1_g  = (const float*)d_in[1];
    const float* ln1_b  = (const float*)d_in[2];
    const float* w_qkv  = (const float*)d_in[3];
    const float* b_qkv  = (const float*)d_in[4];
    const float* w_proj = (const float*)d_in[5];
    const float* b_proj = (const float*)d_in[6];
    const float* ln2_g  = (const float*)d_in[7];
    const float* ln2_b  = (const float*)d_in[8];
    const float* mlp_M  = (const float*)d_in[9];
    const float* mlp_b1 = (const float*)d_in[10];
    const float* w2     = (const float*)d_in[11];
    const float* b2     = (const float*)d_in[12];
    float* out = (float*)d_out;

    const int M = 64 * 341;  // 21824 rows

    char* ws = (char*)d_ws;
    size_t off = 0;
    auto alloc = [&](size_t bytes) -> char* {
        char* p = ws + off;
        off += (bytes + 255) & ~(size_t)255;
        return p;
    };
    __hip_bfloat16* xn     = (__hip_bfloat16*)alloc((size_t)M * 512 * 2);
    __hip_bfloat16* wqkvT  = (__hip_bfloat16*)alloc(1536ull * 512 * 2);
    __hip_bfloat16* wprojT = (__hip_bfloat16*)alloc(512ull * 512 * 2);
    __hip_bfloat16* w2T    = (__hip_bfloat16*)alloc(512ull * 2048 * 2);
    __hip_bfloat16* wcat   = (__hip_bfloat16*)alloc(15ull * 2048 * 512 * 2);
    __hip_bfloat16* hbuf   = (__hip_bfloat16*)alloc((size_t)M * 2048 * 2);
    // shared region: qkv+ctx (attention phase) overlaid by Y (branch phase)
    const size_t qkv_bytes = (size_t)M * 1536 * 2;            // 67,043,328
    const size_t y_bytes   = 59375616ull * 2;                 // 118,751,232
    char* shared = alloc(y_bytes);                            // >= qkv+ctx
    __hip_bfloat16* qkv = (__hip_bfloat16*)shared;
    __hip_bfloat16* ctx = (__hip_bfloat16*)(shared + qkv_bytes);
    __hip_bfloat16* Y   = (__hip_bfloat16*)shared;
    if (off > ws_size) return;  // workspace too small -> clean validation failure

    auto g64 = [&](const __hip_bfloat16* A, const __hip_bfloat16* Bt,
                   const float* bias, const float* resid, float* Cf,
                   __hip_bfloat16* Cb, int Mr, int N, int K, int flags) {
        int gm = (Mr + 63) >> 6, gn = N >> 7;
        gemm64<<<dim3(gm * gn), 256, 0, stream>>>(
            A, Bt, bias, resid, Cf, Cb, Mr, N, K, flags, gn);
    };

    // fused weight prep (one dispatch)
    prep_kernel<<<dim3(17408), 256, 0, stream>>>(w_qkv, w_proj, w2, mlp_M,
                                                 wqkvT, wprojT, w2T, wcat);

    // attention path (qkv on gemm64: R13-isolated win)
    ln_kernel<<<M, 256, 0, stream>>>(x, ln1_g, ln1_b, xn);
    g64(xn, wqkvT, b_qkv, nullptr, nullptr, qkv, M, 1536, 512, GF_OUTBF16);
    attn_mfma_kernel<<<dim3(512, 2), 256, 0, stream>>>(qkv, ctx);
    g64(ctx, wprojT, b_proj, x, out, nullptr, M, 512, 512, 0);

    // branch MLP path (dedup by source depth s) — single fused dispatch
    ln_kernel<<<M, 256, 0, stream>>>(out, ln2_g, ln2_b, xn);
    gemm_branch_fused<<<dim3(3664), 256, 0, stream>>>(xn, wcat, Y);
    combine_kernel<<<M, 256, 0, stream>>>(Y, mlp_b1, hbuf);
    g64(hbuf, w2T, b2, out, out, nullptr, M, 512, 2048, 0);
}